// Round 10
// baseline (183.845 us; speedup 1.0000x reference)
//
#include <hip/hip_runtime.h>
#include <hip/hip_bf16.h>

// Problem constants
#define N_TOK 8192
#define INL   512
#define OUTL  512
#define NE    8
#define NI    16
#define EOFF  (OUTL * INL)   // elems per expert in wt

typedef unsigned short ushort_t;
typedef unsigned int   uint_t;
typedef short  short8  __attribute__((ext_vector_type(8)));
typedef float  floatx4 __attribute__((ext_vector_type(4)));

// ---------------- workspace layout (bytes) ----------------
#define WS_GAM    2048u      // float[8]  : gam[e]
#define WS_RGAM   2080u      // float[8]  : router_gamma[e]
#define WS_BET    2112u      // float[4096] : bet_eff[e][d] = bet + gam*b
#define WS_WT     182336u    // ushort[8*512*512] : W^T bf16 [e][d][l]

__device__ __forceinline__ ushort_t f2bf(float f) {
    uint_t b = __float_as_uint(f);
    return (ushort_t)((b + 0x7FFFu + ((b >> 16) & 1u)) >> 16);   // RNE
}
__device__ __forceinline__ uint_t pkbf(float a, float b) {
    __hip_bfloat162 h = __float22bfloat162_rn(make_float2(a, b));  // v_cvt_pk_bf16_f32
    union { __hip_bfloat162 h2; uint_t u; } cv;
    cv.h2 = h;
    return cv.u;
}
// async global->LDS DMA, 16 B per lane; LDS dest = wave-uniform base + lane*16
__device__ __forceinline__ void dma16(const ushort_t* g, ushort_t* l) {
    __builtin_amdgcn_global_load_lds(
        (const __attribute__((address_space(1))) void*)g,
        (__attribute__((address_space(3))) void*)l,
        16, 0, 0);
}

// ================= K1: fused prep (no router) =================
// blocks [0,512):   Wt transpose/convert  (e = bx>>6; tile = bx&63)
// blocks [512,640): bet_eff               (e = b>>4; dBase = (b&15)*32)
// block  640:       stats -> wsGam, wsRgam
__global__ __launch_bounds__(256)
void k_prep(const float* __restrict__ ins,
            const float* __restrict__ expert_w,
            const float* __restrict__ expert_b,
            const float* __restrict__ gamma_w,
            const float* __restrict__ beta_w,
            const float* __restrict__ rmod_w,
            ushort_t* __restrict__ wt,
            float* __restrict__ wsBet,
            float* __restrict__ wsGam, float* __restrict__ wsRgam) {
    __shared__ __align__(16) char smem[17152];
    int bx = blockIdx.x;
    int tid = threadIdx.x;

    if (bx < 512) {
        // ---- Wt: [e][l][d] fp32 -> [e][d][l] bf16 ----
        float (*tile)[65] = (float(*)[65])smem;
        int e = bx >> 6, rem = bx & 63;
        int lt = (rem >> 3) * 64, dt = (rem & 7) * 64;
        int dIdx = tid & 63, lq = tid >> 6;
        for (int i = 0; i < 16; ++i) {
            int l = lq * 16 + i;
            tile[l][dIdx] = expert_w[(e * INL + lt + l) * OUTL + dt + dIdx];
        }
        __syncthreads();
        int lIdx = tid & 63, dq = tid >> 6;
        for (int i = 0; i < 16; ++i) {
            int d = dq * 16 + i;
            wt[(e * OUTL + dt + d) * INL + lt + lIdx] = f2bf(tile[lIdx][d]);
        }
        return;
    }

    if (bx < 640) {
        // ---- bet_eff[e][d] = (1/NI) sum_h s[h] beta[e,h,d] + gam_e * b[e,d] ----
        float* sS  = (float*)smem;          // [512]
        float* red = sS + 512;              // [256]
        float* gamS = red + 256;            // [1]
        int b2 = bx - 512;
        int e = b2 >> 4, dBase = (b2 & 15) * 32;
        for (int h = tid; h < INL; h += 256) {
            float a = 0.f;
            for (int n = 0; n < NI; ++n) a += ins[n * INL + h];
            sS[h] = a;
        }
        __syncthreads();
        if (tid < 64) {
            float g = 0.f;
            for (int j = 0; j < 8; ++j) g += sS[tid * 8 + j] * gamma_w[e * INL + tid * 8 + j];
            for (int off = 32; off >= 1; off >>= 1) g += __shfl_xor(g, off, 64);
            if (tid == 0) gamS[0] = g * (1.f / NI);
        }
        int doff = tid & 31, hq = tid >> 5;
        float a = 0.f;
        for (int j = 0; j < 64; ++j) {
            int h = hq * 64 + j;
            a += sS[h] * beta_w[(e * INL + h) * OUTL + dBase + doff];
        }
        red[tid] = a;
        __syncthreads();
        if (tid < 32) {
            float t = 0.f;
            for (int k = 0; k < 8; ++k) t += red[k * 32 + tid];
            int d = dBase + tid;
            wsBet[e * OUTL + d] = t * (1.f / NI) + gamS[0] * expert_b[e * OUTL + d];
        }
        return;
    }

    // ---- stats: gam[e], rgam[e] ----
    {
        float* sS = (float*)smem;           // [512]
        float* pg = sS + 512;               // [64]
        float* pr = pg + 64;                // [64]
        for (int h = tid; h < INL; h += 256) {
            float a = 0.f;
            for (int n = 0; n < NI; ++n) a += ins[n * INL + h];
            sS[h] = a;
        }
        __syncthreads();
        if (tid < 64) {
            int e = tid & 7, qq = tid >> 3;
            float g = 0.f, r = 0.f;
            for (int j = 0; j < 64; ++j) {
                int h = qq * 64 + j;
                float sv = sS[h];
                g += sv * gamma_w[e * INL + h];
                r += sv * rmod_w[h * NE + e];
            }
            pg[tid] = g; pr[tid] = r;
        }
        __syncthreads();
        if (tid < NE) {
            float g = 0.f, r = 0.f;
            for (int qq = 0; qq < 8; ++qq) { g += pg[qq * 8 + tid]; r += pr[qq * 8 + tid]; }
            wsGam[tid]  = g * (1.f / NI);
            wsRgam[tid] = r * (1.f / NI);
        }
    }
}

// ================= K2: dense all-expert GEMM with in-block router =================
// Block = M128 x N64, 4 waves. 32 barrier-steps: (kcp 0..3) x (e 0..7), BK=128.
// Per step: 16 KB B tile DMA'd (dbuf, 32 KB LDS total), 32 MFMA + 96 pack-VALU
// + 16 ds_read per wave.  A: fp32 regs reloaded per kcp (L1-hot), scaled per
// expert, single accumulator.  Phase-0 computes fp32 router logits for the
// block's 128 rows (same lane layout as A), top-2 + softmax in registers.
// LDS rotate swizzle: (col,k) at col*128 + (((k>>3)+col)&15)*8.
__global__ __launch_bounds__(256, 2)
void k_gemm(const float* __restrict__ x, const ushort_t* __restrict__ wt,
            const float* __restrict__ gate_w,
            const float* __restrict__ wsGam, const float* __restrict__ wsRgam,
            const float* __restrict__ wsBet, float* __restrict__ out) {
    int bx = blockIdx.x;
    int rt = bx & 63;                  // token slab: rows rt*128..+128
    int ct = bx >> 6;                  // col slab: ct*64..+64  (0..7)
    __shared__ ushort_t Blds[2 * 8192];   // 32 KB: [buf][col][slot]

    int tid = threadIdx.x;
    int wid = tid >> 6, lane = tid & 63;
    int wm = wid * 32;
    int mrow = lane & 15, laneq = lane >> 4, q8 = laneq * 8, qr = laneq * 4;

    // ---- staging maps: 1024 chunks/tile; thread stages ch = tid + 256*i ----
    const ushort_t* pBsrc[4];
    ushort_t* ldsDst[4];
    for (int i = 0; i < 4; ++i) {
        int ch = tid + 256 * i;
        int col = ch >> 4, slot = ch & 15;
        int kg = (slot - col) & 15;
        pBsrc[i] = wt + (size_t)(ct * 64 + col) * INL + kg * 8;
        ldsDst[i] = &Blds[0] + (size_t)(i * 256 + wid * 64) * 8;  // +buf*8192
    }

    // ---- issue DMA for step 0 (kcp=0, e=0) into buf 0 ----
    for (int i = 0; i < 4; ++i) dma16(pBsrc[i], ldsDst[i]);

    // ---- A row pointers ----
    const float* arow[2];
    for (int mt = 0; mt < 2; ++mt)
        arow[mt] = x + (size_t)(rt * 128 + wm + mt * 16 + mrow) * INL + q8;

    // ---- phase 0: fp32 router for this lane's 2 rows ----
    float ar[2][4][8];    // [mt][ks][j] fp32 A fragments (reused in main loop)
    float lg[2][NE];
    for (int mt = 0; mt < 2; ++mt)
        for (int e = 0; e < NE; ++e) lg[mt][e] = 0.f;
    for (int kcp = 0; kcp < 4; ++kcp) {
        for (int mt = 0; mt < 2; ++mt)
            for (int ks = 0; ks < 4; ++ks) {
                const float* p = arow[mt] + kcp * 128 + ks * 32;
                *(float4*)&ar[mt][ks][0] = *(const float4*)p;
                *(float4*)&ar[mt][ks][4] = *(const float4*)(p + 4);
            }
        for (int ks = 0; ks < 4; ++ks)
            for (int j = 0; j < 8; ++j) {
                int k = kcp * 128 + ks * 32 + q8 + j;
                float4 g0 = *(const float4*)(gate_w + k * NE);
                float4 g1 = *(const float4*)(gate_w + k * NE + 4);
                for (int mt = 0; mt < 2; ++mt) {
                    float a = ar[mt][ks][j];
                    lg[mt][0] += a * g0.x; lg[mt][1] += a * g0.y;
                    lg[mt][2] += a * g0.z; lg[mt][3] += a * g0.w;
                    lg[mt][4] += a * g1.x; lg[mt][5] += a * g1.y;
                    lg[mt][6] += a * g1.z; lg[mt][7] += a * g1.w;
                }
            }
    }
    // reduce over laneq groups (lanes 16/32 apart share the same rows)
    for (int mt = 0; mt < 2; ++mt)
        for (int e = 0; e < NE; ++e) {
            float a = lg[mt][e];
            a += __shfl_xor(a, 16, 64);
            a += __shfl_xor(a, 32, 64);
            lg[mt][e] = a + wsRgam[e];
        }
    // top-2 (lowest-index tie-break), softmax, combine weights
    float wv[2][NE];
    int   esL[2];
    float rwA[2], rwB[2];
    for (int mt = 0; mt < 2; ++mt) {
        int i0 = 0; float m0 = lg[mt][0];
        for (int e = 1; e < NE; ++e) if (lg[mt][e] > m0) { m0 = lg[mt][e]; i0 = e; }
        int i1 = -1; float m1 = -3.4e38f;
        for (int e = 0; e < NE; ++e) if (e != i0 && lg[mt][e] > m1) { m1 = lg[mt][e]; i1 = e; }
        float S = 0.f;
        for (int e = 0; e < NE; ++e) S += expf(lg[mt][e] - m0);
        float rw0 = 1.0f / S;
        float rw1 = expf(m1 - m0) / S;
        for (int e = 0; e < NE; ++e) wv[mt][e] = 0.f;
        wv[mt][i0] = rw0 * wsGam[i0];
        wv[mt][i1] = rw1 * wsGam[i1];
        esL[mt] = i0 | (i1 << 8);
        rwA[mt] = rw0; rwB[mt] = rw1;
    }

    // ---- fragment read swizzle precompute ----
    int cb[4], rotb[4];
    for (int nt = 0; nt < 4; ++nt) {
        int col = nt * 16 + mrow;
        cb[nt] = col * 128;
        rotb[nt] = (laneq + col) & 15;
    }

    floatx4 comb[2][4];
    for (int mt = 0; mt < 2; ++mt)
        for (int nt = 0; nt < 4; ++nt)
            comb[mt][nt] = (floatx4){0.f, 0.f, 0.f, 0.f};

    // ---- main loop: 32 steps of (kcp, e) ----
    #pragma unroll 1
    for (int step = 0; step < 32; ++step) {
        int kcp = step >> 3, e = step & 7, buf = step & 1;
        __syncthreads();   // drains DMA for this buf; prev buf's reads done

        // issue DMA for next step into other buffer (flies under compute)
        if (step < 31) {
            int ns = step + 1;
            size_t off = ((size_t)(ns & 7) << 18) + (size_t)(ns >> 3) * 128;
            int nb = ns & 1;
            for (int i = 0; i < 4; ++i)
                dma16(pBsrc[i] + off, ldsDst[i] + nb * 8192);
        }
        // reload A at each new kcp (L1-hot after phase 0)
        if ((step & 7) == 0) {
            for (int mt = 0; mt < 2; ++mt)
                for (int ks = 0; ks < 4; ++ks) {
                    const float* p = arow[mt] + kcp * 128 + ks * 32;
                    *(float4*)&ar[mt][ks][0] = *(const float4*)p;
                    *(float4*)&ar[mt][ks][4] = *(const float4*)(p + 4);
                }
        }

        const ushort_t* B = &Blds[buf * 8192];
        #pragma unroll
        for (int ks = 0; ks < 4; ++ks) {
            short8 bf[4];
            for (int nt = 0; nt < 4; ++nt) {
                int slot = (rotb[nt] + ks * 4) & 15;
                bf[nt] = *(const short8*)&B[cb[nt] + slot * 8];
            }
            for (int mt = 0; mt < 2; ++mt) {
                float w = wv[mt][e];
                union { uint4 u; short8 s; } af;
                af.u.x = pkbf(ar[mt][ks][0] * w, ar[mt][ks][1] * w);
                af.u.y = pkbf(ar[mt][ks][2] * w, ar[mt][ks][3] * w);
                af.u.z = pkbf(ar[mt][ks][4] * w, ar[mt][ks][5] * w);
                af.u.w = pkbf(ar[mt][ks][6] * w, ar[mt][ks][7] * w);
                for (int nt = 0; nt < 4; ++nt)
                    comb[mt][nt] = __builtin_amdgcn_mfma_f32_16x16x32_bf16(
                        af.s, bf[nt], comb[mt][nt], 0, 0, 0);
            }
        }
    }

    // ---- epilogue: out = comb + rw0*bet[e0] + rw1*bet[e1] (single store) ----
    for (int mt = 0; mt < 2; ++mt) {
        for (int ri = 0; ri < 4; ++ri) {
            int row = wm + mt * 16 + qr + ri;
            int tok = rt * 128 + row;
            int src = (lane & 48) | (qr + ri);
            int es  = __shfl(esL[mt], src, 64);
            float r0 = __shfl(rwA[mt], src, 64);
            float r1 = __shfl(rwB[mt], src, 64);
            int e0 = es & 255, e1 = es >> 8;
            for (int nt = 0; nt < 4; ++nt) {
                int col = ct * 64 + nt * 16 + mrow;
                float bet = r0 * wsBet[e0 * OUTL + col] + r1 * wsBet[e1 * OUTL + col];
                out[(size_t)tok * OUTL + col] = comb[mt][nt][ri] + bet;
            }
        }
    }
}

extern "C" void kernel_launch(void* const* d_in, const int* in_sizes, int n_in,
                              void* d_out, int out_size, void* d_ws, size_t ws_size,
                              hipStream_t stream) {
    const float* x        = (const float*)d_in[0];
    const float* ins      = (const float*)d_in[1];
    const float* gate_w   = (const float*)d_in[2];
    const float* expert_w = (const float*)d_in[3];
    const float* expert_b = (const float*)d_in[4];
    const float* gamma_w  = (const float*)d_in[5];
    const float* beta_w   = (const float*)d_in[6];
    const float* rmod_w   = (const float*)d_in[7];
    float* out = (float*)d_out;

    char* ws = (char*)d_ws;
    float*    wsGam  = (float*)(ws + WS_GAM);
    float*    wsRgam = (float*)(ws + WS_RGAM);
    float*    wsBet  = (float*)(ws + WS_BET);
    ushort_t* wt     = (ushort_t*)(ws + WS_WT);

    k_prep<<<641, 256, 0, stream>>>(ins, expert_w, expert_b,
                                    gamma_w, beta_w, rmod_w,
                                    wt, wsBet, wsGam, wsRgam);
    k_gemm<<<512, 256, 0, stream>>>(x, wt, gate_w, wsGam, wsRgam, wsBet, out);
}

// Round 11
// 150.844 us; speedup vs baseline: 1.2188x; 1.2188x over previous
//
#include <hip/hip_runtime.h>
#include <hip/hip_bf16.h>

// Problem constants
#define N_TOK 8192
#define INL   512
#define OUTL  512
#define NE    8
#define NI    16
#define EOFF  (OUTL * INL)   // elems per expert in wt

typedef unsigned short ushort_t;
typedef unsigned int   uint_t;
typedef short  short8  __attribute__((ext_vector_type(8)));
typedef float  floatx4 __attribute__((ext_vector_type(4)));

// ---------------- workspace layout (bytes) ----------------
#define WS_GAM    2048u      // float[8]   : gam[e]
#define WS_RGAM   2080u      // float[8]   : router_gamma[e]
#define WS_BET    2112u      // float[4096]: bet_eff[e][d] = bet + gam*b
#define WS_SELE   18496u     // int[8192]  : e0 | e1<<8
#define WS_SELW   51264u     // float4[8192]: {rw0*gam0, rw1*gam1, rw0, rw1}
#define WS_WT     182336u    // ushort[8*512*512] : W^T bf16 [e][d][l]

__device__ __forceinline__ ushort_t f2bf(float f) {
    uint_t b = __float_as_uint(f);
    return (ushort_t)((b + 0x7FFFu + ((b >> 16) & 1u)) >> 16);   // RNE
}
__device__ __forceinline__ uint_t pkbf(float a, float b) {
    __hip_bfloat162 h = __float22bfloat162_rn(make_float2(a, b));  // v_cvt_pk_bf16_f32
    union { __hip_bfloat162 h2; uint_t u; } cv;
    cv.h2 = h;
    return cv.u;
}
// async global->LDS DMA, 16 B per lane; LDS dest = wave-uniform base + lane*16
__device__ __forceinline__ void dma16(const ushort_t* g, ushort_t* l) {
    __builtin_amdgcn_global_load_lds(
        (const __attribute__((address_space(1))) void*)g,
        (__attribute__((address_space(3))) void*)l,
        16, 0, 0);
}

// ================= K1: fused prep =================
// blocks [0,512):   Wt transpose/convert  (e = bx>>6; tile = bx&63)
// blocks [512,640): bet_eff               (e = b>>4; dBase = (b&15)*32)
// block  640:       stats -> wsGam, wsRgam
__global__ __launch_bounds__(256)
void k_prep(const float* __restrict__ ins,
            const float* __restrict__ expert_w,
            const float* __restrict__ expert_b,
            const float* __restrict__ gamma_w,
            const float* __restrict__ beta_w,
            const float* __restrict__ rmod_w,
            ushort_t* __restrict__ wt,
            float* __restrict__ wsBet,
            float* __restrict__ wsGam, float* __restrict__ wsRgam) {
    __shared__ __align__(16) char smem[17152];
    int bx = blockIdx.x;
    int tid = threadIdx.x;

    if (bx < 512) {
        float (*tile)[65] = (float(*)[65])smem;
        int e = bx >> 6, rem = bx & 63;
        int lt = (rem >> 3) * 64, dt = (rem & 7) * 64;
        int dIdx = tid & 63, lq = tid >> 6;
        for (int i = 0; i < 16; ++i) {
            int l = lq * 16 + i;
            tile[l][dIdx] = expert_w[(e * INL + lt + l) * OUTL + dt + dIdx];
        }
        __syncthreads();
        int lIdx = tid & 63, dq = tid >> 6;
        for (int i = 0; i < 16; ++i) {
            int d = dq * 16 + i;
            wt[(e * OUTL + dt + d) * INL + lt + lIdx] = f2bf(tile[lIdx][d]);
        }
        return;
    }

    if (bx < 640) {
        float* sS  = (float*)smem;          // [512]
        float* red = sS + 512;              // [256]
        float* gamS = red + 256;            // [1]
        int b2 = bx - 512;
        int e = b2 >> 4, dBase = (b2 & 15) * 32;
        for (int h = tid; h < INL; h += 256) {
            float a = 0.f;
            for (int n = 0; n < NI; ++n) a += ins[n * INL + h];
            sS[h] = a;
        }
        __syncthreads();
        if (tid < 64) {
            float g = 0.f;
            for (int j = 0; j < 8; ++j) g += sS[tid * 8 + j] * gamma_w[e * INL + tid * 8 + j];
            for (int off = 32; off >= 1; off >>= 1) g += __shfl_xor(g, off, 64);
            if (tid == 0) gamS[0] = g * (1.f / NI);
        }
        int doff = tid & 31, hq = tid >> 5;
        float a = 0.f;
        for (int j = 0; j < 64; ++j) {
            int h = hq * 64 + j;
            a += sS[h] * beta_w[(e * INL + h) * OUTL + dBase + doff];
        }
        red[tid] = a;
        __syncthreads();
        if (tid < 32) {
            float t = 0.f;
            for (int k = 0; k < 8; ++k) t += red[k * 32 + tid];
            int d = dBase + tid;
            wsBet[e * OUTL + d] = t * (1.f / NI) + gamS[0] * expert_b[e * OUTL + d];
        }
        return;
    }

    {   // stats
        float* sS = (float*)smem;           // [512]
        float* pg = sS + 512;               // [64]
        float* pr = pg + 64;                // [64]
        for (int h = tid; h < INL; h += 256) {
            float a = 0.f;
            for (int n = 0; n < NI; ++n) a += ins[n * INL + h];
            sS[h] = a;
        }
        __syncthreads();
        if (tid < 64) {
            int e = tid & 7, qq = tid >> 3;
            float g = 0.f, r = 0.f;
            for (int j = 0; j < 64; ++j) {
                int h = qq * 64 + j;
                float sv = sS[h];
                g += sv * gamma_w[e * INL + h];
                r += sv * rmod_w[h * NE + e];
            }
            pg[tid] = g; pr[tid] = r;
        }
        __syncthreads();
        if (tid < NE) {
            float g = 0.f, r = 0.f;
            for (int qq = 0; qq < 8; ++qq) { g += pg[qq * 8 + tid]; r += pr[qq * 8 + tid]; }
            wsGam[tid]  = g * (1.f / NI);
            wsRgam[tid] = r * (1.f / NI);
        }
    }
}

// ================= K2: router (fp32 logits), 16 tokens/block =================
__global__ void k_route(const float* __restrict__ x,
                        const float* __restrict__ gate_w,
                        const float* __restrict__ wsGam,
                        const float* __restrict__ wsRgam,
                        int* __restrict__ selE, float4* __restrict__ selW) {
    __shared__ float gateT[NE * INL];   // 16 KB, [e][l]
    int tid = threadIdx.x;
    for (int i = 0; i < 16; ++i) {
        int f = tid + 256 * i;
        float v = gate_w[f];
        gateT[(f & 7) * INL + (f >> 3)] = v;
    }
    __syncthreads();

    int w = tid >> 6, lane = tid & 63;
    int tbase = blockIdx.x * 16 + w * 4;

    for (int tt = 0; tt < 4; ++tt) {
        int t = tbase + tt;
        float2 xv[4];
        for (int i = 0; i < 4; ++i)
            xv[i] = *(const float2*)(x + (size_t)t * INL + 2 * lane + 128 * i);

        float acc[NE];
        for (int e = 0; e < NE; ++e) acc[e] = 0.f;
        for (int i = 0; i < 4; ++i) {
            int c = 2 * lane + 128 * i;
            for (int e = 0; e < NE; ++e)
                acc[e] += xv[i].x * gateT[e * INL + c] + xv[i].y * gateT[e * INL + c + 1];
        }
        for (int e = 0; e < NE; ++e) {
            float a = acc[e];
            for (int off = 32; off >= 1; off >>= 1) a += __shfl_xor(a, off, 64);
            acc[e] = a;
        }
        float logit[NE];
        for (int e = 0; e < NE; ++e) logit[e] = acc[e] + wsRgam[e];

        int i0 = 0; float m0 = logit[0];
        for (int e = 1; e < NE; ++e) if (logit[e] > m0) { m0 = logit[e]; i0 = e; }
        int i1 = -1; float m1 = -3.4e38f;
        for (int e = 0; e < NE; ++e) if (e != i0 && logit[e] > m1) { m1 = logit[e]; i1 = e; }

        float S = 0.f;
        for (int e = 0; e < NE; ++e) S += expf(logit[e] - m0);
        float rw0 = 1.0f / S;
        float rw1 = expf(m1 - m0) / S;

        if (lane == 0) {
            selE[t] = i0 | (i1 << 8);
            selW[t] = make_float4(rw0 * wsGam[i0], rw1 * wsGam[i1], rw0, rw1);
        }
    }
}

// ================= K3: dense all-expert GEMM =================
// r8 step structure bit-for-bit (proven 0-conflict swizzle), but M64xN64
// blocks -> grid 1024 = 4 blocks/CU (LB(256,4), 16 KB LDS). While one block
// drains its DMA at the barrier, 3 co-resident blocks keep the SIMDs fed
// (TLP-based latency hiding, m114).
__global__ __launch_bounds__(256, 4)
void k_gemm(const float* __restrict__ x, const ushort_t* __restrict__ wt,
            const int* __restrict__ selE, const float4* __restrict__ selW,
            const float* __restrict__ wsBet, float* __restrict__ out) {
    int bx = blockIdx.x;
    int rt = bx & 127;                 // token slab: rows rt*64..+64
    int ct = bx >> 7;                  // col slab: ct*64..+64
    __shared__ ushort_t Blds[2][64 * 64];   // 2 x 8 KB, swizzled [col][slot]

    int tid = threadIdx.x;
    int wid = tid >> 6, lane = tid & 63;
    int wm = wid * 16;                 // wave's 16-row slice
    int mrow = lane & 15, laneq = lane >> 4, q8 = laneq * 8, qr = laneq * 4;

    // combine weights for this lane's A row
    int tokL = rt * 64 + wm + mrow;
    float wv[NE];
    {
        int es = selE[tokL];
        float4 w4 = selW[tokL];
        int e0 = es & 255, e1 = es >> 8;
        for (int e = 0; e < NE; ++e)
            wv[e] = (e == e0) ? w4.x : ((e == e1) ? w4.y : 0.f);
    }
    const float* arowp = x + (size_t)tokL * INL + q8;

    // B staging: thread stages chunks c0=tid, c1=tid+256 (chunk = 8 k, 16 B)
    // chunk c -> col=c>>3, kslot=c&7, src kgrp=(kslot-col)&7  (rotate swizzle)
    int c0 = tid, c1 = tid + 256;
    int col0 = c0 >> 3, kg0 = ((c0 & 7) - col0) & 7;
    int col1 = c1 >> 3, kg1 = ((c1 & 7) - col1) & 7;
    const ushort_t* pB0 = wt + (size_t)(ct * 64 + col0) * INL + kg0 * 8;
    const ushort_t* pB1 = wt + (size_t)(ct * 64 + col1) * INL + kg1 * 8;
    ushort_t* ldsW0 = &Blds[0][0] + (wid * 64) * 8;        // + buf*4096
    ushort_t* ldsW1 = &Blds[0][0] + (256 + wid * 64) * 8;

    // fragment read swizzle
    int fcol[4], frot0[4];
    for (int nt = 0; nt < 4; ++nt) {
        fcol[nt] = nt * 16 + mrow;
        frot0[nt] = (laneq + fcol[nt]) & 7;
    }

    floatx4 comb[4];
    for (int nt = 0; nt < 4; ++nt) comb[nt] = (floatx4){0.f, 0.f, 0.f, 0.f};

    // prologue: DMA tile (kc=0,e=0) into buf0, drain
    dma16(pB0, ldsW0);
    dma16(pB1, ldsW1);
    __syncthreads();

    float4 ar[2][2];   // [ks][half] fp32 A fragments for current kc

    #pragma unroll 1
    for (int kc = 0; kc < 8; ++kc) {
        for (int ks = 0; ks < 2; ++ks) {
            const float* p = arowp + kc * 64 + ks * 32;
            ar[ks][0] = *(const float4*)p;
            ar[ks][1] = *(const float4*)(p + 4);
        }

        #pragma unroll
        for (int e = 0; e < NE; ++e) {
            int step = kc * 8 + e;
            int buf = step & 1;
            // issue DMA for next step into the other buffer (flies under compute)
            int ne = e + 1, nkc = kc;
            if (ne == NE) { ne = 0; nkc = kc + 1; }
            if (nkc < 8) {
                size_t off = (size_t)ne * EOFF + (size_t)nkc * 64;
                int nb = (step + 1) & 1;
                dma16(pB0 + off, ldsW0 + nb * 4096);
                dma16(pB1 + off, ldsW1 + nb * 4096);
            }

            // compute current step from buf
            const ushort_t* B = &Blds[buf][0];
            short8 bf[4][2];
            for (int nt = 0; nt < 4; ++nt) {
                int cb = fcol[nt] * 64;
                bf[nt][0] = *(const short8*)&B[cb + frot0[nt] * 8];
                bf[nt][1] = *(const short8*)&B[cb + ((frot0[nt] + 4) & 7) * 8];
            }
            float w = wv[e];
            for (int ks = 0; ks < 2; ++ks) {
                union { uint4 u; short8 s; } af;
                float4 a0 = ar[ks][0], a1 = ar[ks][1];
                af.u.x = pkbf(a0.x * w, a0.y * w);
                af.u.y = pkbf(a0.z * w, a0.w * w);
                af.u.z = pkbf(a1.x * w, a1.y * w);
                af.u.w = pkbf(a1.z * w, a1.w * w);
                for (int nt = 0; nt < 4; ++nt)
                    comb[nt] = __builtin_amdgcn_mfma_f32_16x16x32_bf16(
                        af.s, bf[nt][ks], comb[nt], 0, 0, 0);
            }
            __syncthreads();   // drain next-DMA (overlapped) + release buf readers
        }
    }

    // epilogue: out = comb + rw0*bet_eff[e0] + rw1*bet_eff[e1], single store
    for (int ri = 0; ri < 4; ++ri) {
        int row = wm + qr + ri;
        int tok = rt * 64 + row;
        int es = selE[tok];
        float4 w4 = selW[tok];
        int e0 = es & 255, e1 = es >> 8;
        for (int nt = 0; nt < 4; ++nt) {
            int col = ct * 64 + nt * 16 + mrow;
            float bet = w4.z * wsBet[e0 * OUTL + col] + w4.w * wsBet[e1 * OUTL + col];
            out[(size_t)tok * OUTL + col] = comb[nt][ri] + bet;
        }
    }
}

extern "C" void kernel_launch(void* const* d_in, const int* in_sizes, int n_in,
                              void* d_out, int out_size, void* d_ws, size_t ws_size,
                              hipStream_t stream) {
    const float* x        = (const float*)d_in[0];
    const float* ins      = (const float*)d_in[1];
    const float* gate_w   = (const float*)d_in[2];
    const float* expert_w = (const float*)d_in[3];
    const float* expert_b = (const float*)d_in[4];
    const float* gamma_w  = (const float*)d_in[5];
    const float* beta_w   = (const float*)d_in[6];
    const float* rmod_w   = (const float*)d_in[7];
    float* out = (float*)d_out;

    char* ws = (char*)d_ws;
    float*    wsGam  = (float*)(ws + WS_GAM);
    float*    wsRgam = (float*)(ws + WS_RGAM);
    float*    wsBet  = (float*)(ws + WS_BET);
    int*      selE   = (int*)(ws + WS_SELE);
    float4*   selW   = (float4*)(ws + WS_SELW);
    ushort_t* wt     = (ushort_t*)(ws + WS_WT);

    k_prep<<<641, 256, 0, stream>>>(ins, expert_w, expert_b,
                                    gamma_w, beta_w, rmod_w,
                                    wt, wsBet, wsGam, wsRgam);
    k_route<<<N_TOK / 16, 256, 0, stream>>>(x, gate_w, wsGam, wsRgam, selE, selW);
    k_gemm<<<1024, 256, 0, stream>>>(x, wt, selE, selW, wsBet, out);
}